// Round 3
// baseline (34945.181 us; speedup 1.0000x reference)
//
#include <hip/hip_runtime.h>
#include <hip/hip_bf16.h>

typedef _Float16 half_t;
typedef _Float16 half2_t __attribute__((ext_vector_type(2)));
typedef unsigned int       u32;
typedef unsigned short     u16;
typedef unsigned long long u64;

#define BB    32      // batch
#define TT    2048    // seq len
#define HH    256     // hidden = input dim
#define G3    768     // 3*H
#define DEPTH 4       // ring-buffer depth (power of 2)

// ws layout (bytes) — total 856064:
//   0      : flags[3][BB][DEPTH] u32  (1536)   link: 0=S0->S1 (xg0), 1=S1->S2 (h0), 2=S2->S3 (xg1)
//   2048   : cons [3][BB]        u32  (384)    consumer progress per link
//   4096   : xg0q [BB][DEPTH][G3] f32 (393216)
//   397312 : xg1q [BB][DEPTH][G3] f32 (393216)
//   790528 : h0q  [BB][DEPTH][HH] f16 (65536)
#define OFF_CONS 2048
#define OFF_XG0  4096
#define OFF_XG1  397312
#define OFF_H0   790528
#define FLAGS_BYTES 4096

__device__ __forceinline__ float bf2f(u16 u) {
  return __uint_as_float(((u32)u) << 16);
}
__device__ __forceinline__ half2_t bf2h2(u32 u) {
  float lo = __uint_as_float(u << 16);
  float hi = __uint_as_float(u & 0xffff0000u);
  half2_t r; r.x = (half_t)lo; r.y = (half_t)hi; return r;
}
__device__ __forceinline__ half2_t f2h2(float a, float b) {
  half2_t r; r.x = (half_t)a; r.y = (half_t)b; return r;
}
__device__ __forceinline__ float sigm(float v) {
  return __builtin_amdgcn_rcpf(1.f + __builtin_amdgcn_exp2f(v * -1.4426950408889634f));
}
__device__ __forceinline__ float tanh_fast(float v) {
  return 1.f - 2.f * __builtin_amdgcn_rcpf(1.f + __builtin_amdgcn_exp2f(v * 2.8853900817779268f));
}
__device__ __forceinline__ void wait_ge(u32* p, u32 v) {
  while (__hip_atomic_load(p, __ATOMIC_ACQUIRE, __HIP_MEMORY_SCOPE_AGENT) < v)
    __builtin_amdgcn_s_sleep(1);
}

// 128 blocks: blockIdx = stage*32 + chain.
//   stage 0: xg0 = Wih0@x_t + bih0       stage 1: GRU cell layer 0 (Whh0)
//   stage 2: xg1 = Wih1@h0_t + bih1      stage 3: GRU cell layer 1 (Whh1) -> out (fp32)
// Thread (i=tid>>1, c=tid&1) owns rows {i, 256+i, 512+i} x K-half c; weights in 192 VGPRs
// as f16 pairs; GEMV via v_dot2_f32_f16; fp32 accumulation and gate math.
__global__ __launch_bounds__(512, 2)
void gru_pipe(const void* __restrict__ x,     // [B][T][H]   fp32 (bf16 auto-detected)
              const void* __restrict__ Wih,   // [2][768][256]
              const void* __restrict__ Whh,   // [2][768][256]
              const void* __restrict__ bih,   // [2][768]
              const void* __restrict__ bhh,   // [2][768]
              float* __restrict__ out,        // fp32 [B][T][H]
              uint8_t* __restrict__ ws)
{
  const int stage = blockIdx.x >> 5;
  const int chain = blockIdx.x & 31;
  const int tid   = threadIdx.x;
  const int i     = tid >> 1;   // 0..255
  const int c     = tid & 1;    // k-half
  const int l     = stage >> 1; // layer
  const bool rec  = (stage & 1);

  u32*    flags = (u32*)ws;
  u32*    cons  = (u32*)(ws + OFF_CONS);
  float*  xg0q  = (float*)(ws + OFF_XG0);
  float*  xg1q  = (float*)(ws + OFF_XG1);
  half_t* h0q   = (half_t*)(ws + OFF_H0);

  // ---- runtime input-dtype detection (fp32 vs bf16 storage), block-uniform ----
  __shared__ int scnt[3];
  if (tid < 3) scnt[tid] = 0;
  __syncthreads();
  {
    u16 vx = ((const u16*)x)[tid];
    u16 vw = ((const u16*)Wih)[tid];
    u16 vb = ((const u16*)bih)[tid];
    u64 mx = __ballot(((vx >> 7) & 0xFF) > 140);
    u64 mw = __ballot(((vw >> 7) & 0xFF) > 140);
    u64 mb = __ballot(((vb >> 7) & 0xFF) > 140);
    if ((tid & 63) == 0) {
      atomicAdd(&scnt[0], (int)__popcll(mx));
      atomicAdd(&scnt[1], (int)__popcll(mw));
      atomicAdd(&scnt[2], (int)__popcll(mb));
    }
  }
  __syncthreads();
  const bool fx = scnt[0] >= 16;   // x is fp32
  const bool fw = scnt[1] >= 16;   // weights are fp32
  const bool fb = scnt[2] >= 16;   // biases are fp32
  __syncthreads();

  const size_t woff = (size_t)l * G3 * HH;
  const void* Wm = rec ? Whh : Wih;
  const void* bv = rec ? bhh : bih;

  // ---- weights -> registers (-> f16: exact for bf16 source, RNE for fp32) ----
  half2_t w[3][64];
  float   bs[3];
#pragma unroll
  for (int r = 0; r < 3; ++r) {
    const int row = r * 256 + i;
    if (!fw) {
      const u32* wp = (const u32*)((const u16*)Wm + woff + (size_t)row * HH + c * 128);
#pragma unroll
      for (int j4 = 0; j4 < 16; ++j4) {
        uint4 v = ((const uint4*)wp)[j4];
        w[r][j4 * 4 + 0] = bf2h2(v.x);
        w[r][j4 * 4 + 1] = bf2h2(v.y);
        w[r][j4 * 4 + 2] = bf2h2(v.z);
        w[r][j4 * 4 + 3] = bf2h2(v.w);
      }
    } else {
      const float* wp = (const float*)Wm + woff + (size_t)row * HH + c * 128;
#pragma unroll
      for (int j4 = 0; j4 < 32; ++j4) {
        float4 v = ((const float4*)wp)[j4];
        w[r][j4 * 2 + 0] = f2h2(v.x, v.y);
        w[r][j4 * 2 + 1] = f2h2(v.z, v.w);
      }
    }
    bs[r] = fb ? ((const float*)bv)[l * G3 + row]
               : bf2f(((const u16*)bv)[l * G3 + row]);
  }

  __shared__ __align__(16) half2_t hb[2][128];   // ping-pong input vector (256 f16)
  if (tid < 128) {
    half2_t z; z.x = (half_t)0.f; z.y = (half_t)0.f;
    hb[0][tid] = z; hb[1][tid] = z;
  }
  __syncthreads();

  float   hprev = 0.f;
  half2_t xreg; xreg.x = (half_t)0.f; xreg.y = (half_t)0.f;
  if (stage == 0 && tid < 128) {
    if (fx) { float2 v = ((const float2*)x)[(size_t)(chain * TT) * 128 + tid]; xreg = f2h2(v.x, v.y); }
    else    { xreg = bf2h2(((const u32*)x)[(size_t)(chain * TT) * 128 + tid]); }
  }

  float* xgq_in  = (stage == 1) ? xg0q : xg1q;
  float* xgq_out = (stage == 0) ? xg0q : xg1q;

  for (int t = 0; t < TT; ++t) {
    const int slot = t & (DEPTH - 1);
    float xr = 0.f, xz = 0.f, xn = 0.f;

    // ---- input / flow control ----
    if (stage == 0) {
      if (t >= DEPTH) wait_ge(&cons[chain], (u32)(t - DEPTH + 1));
      if (tid < 128) hb[t & 1][tid] = xreg;
    } else {
      wait_ge(&flags[((stage - 1) * BB + chain) * DEPTH + slot], (u32)(t + 1));
      if (stage == 2) {
        if (t >= DEPTH) wait_ge(&cons[2 * BB + chain], (u32)(t - DEPTH + 1));
        if (tid < 128) {
          u32 v = ((const u32*)(h0q + ((size_t)chain * DEPTH + slot) * HH))[tid];
          hb[t & 1][tid] = __builtin_bit_cast(half2_t, v);
        }
      } else {
        if (stage == 1 && t >= DEPTH) wait_ge(&cons[BB + chain], (u32)(t - DEPTH + 1));
        if (c == 0) {   // prefetch gate inputs; consumed after the dot loop
          const float* q = xgq_in + ((size_t)chain * DEPTH + slot) * G3;
          xr = q[i]; xz = q[256 + i]; xn = q[512 + i];
        }
      }
    }
    __syncthreads();

    // S0: prefetch next x row (overlaps the dot loop)
    if (stage == 0 && tid < 128 && t + 1 < TT) {
      if (fx) { float2 v = ((const float2*)x)[(size_t)(chain * TT + t + 1) * 128 + tid]; xreg = f2h2(v.x, v.y); }
      else    { xreg = bf2h2(((const u32*)x)[(size_t)(chain * TT + t + 1) * 128 + tid]); }
    }

    // ---- GEMV: 3 rows x 128 k per thread, v_dot2_f32_f16 ----
    float a0 = 0.f, a1 = 0.f, a2 = 0.f;
    const float4* hv4 = (const float4*)&hb[t & 1][c * 64];
#pragma unroll
    for (int j4 = 0; j4 < 16; ++j4) {
      float4 q = hv4[j4];
      half2_t hh[4];
      hh[0] = __builtin_bit_cast(half2_t, q.x);
      hh[1] = __builtin_bit_cast(half2_t, q.y);
      hh[2] = __builtin_bit_cast(half2_t, q.z);
      hh[3] = __builtin_bit_cast(half2_t, q.w);
#pragma unroll
      for (int u = 0; u < 4; ++u) {
        a0 = __builtin_amdgcn_fdot2(w[0][j4 * 4 + u], hh[u], a0, false);
        a1 = __builtin_amdgcn_fdot2(w[1][j4 * 4 + u], hh[u], a1, false);
        a2 = __builtin_amdgcn_fdot2(w[2][j4 * 4 + u], hh[u], a2, false);
      }
    }
    a0 += __shfl_xor(a0, 1, 64);
    a1 += __shfl_xor(a1, 1, 64);
    a2 += __shfl_xor(a2, 1, 64);

    // ---- epilogue ----
    if (c == 0) {
      if (!rec) {
        float* q = xgq_out + ((size_t)chain * DEPTH + slot) * G3;
        q[i]       = a0 + bs[0];
        q[256 + i] = a1 + bs[1];
        q[512 + i] = a2 + bs[2];
      } else {
        float r    = sigm(xr + a0 + bs[0]);
        float z    = sigm(xz + a1 + bs[1]);
        float n    = tanh_fast(xn + r * (a2 + bs[2]));
        float hnew = n + z * (hprev - n);
        hprev = hnew;
        ((half_t*)&hb[(t + 1) & 1][0])[i] = (half_t)hnew;   // state for next step's dot
        if (stage == 1)
          h0q[((size_t)chain * DEPTH + slot) * HH + i] = (half_t)hnew;
        else
          out[(size_t)(chain * TT + t) * HH + i] = hnew;    // fp32 output
      }
    }
    __syncthreads();   // all waves' stores drained (vmcnt(0) before s_barrier) before publish

    if (tid == 0) {
      if (stage < 3)
        __hip_atomic_store(&flags[(stage * BB + chain) * DEPTH + slot], (u32)(t + 1),
                           __ATOMIC_RELEASE, __HIP_MEMORY_SCOPE_AGENT);
      if (stage > 0)
        __hip_atomic_store(&cons[(stage - 1) * BB + chain], (u32)(t + 1),
                           __ATOMIC_RELAXED, __HIP_MEMORY_SCOPE_AGENT);
    }
  }
}

extern "C" void kernel_launch(void* const* d_in, const int* in_sizes, int n_in,
                              void* d_out, int out_size, void* d_ws, size_t ws_size,
                              hipStream_t stream) {
  hipMemsetAsync(d_ws, 0, FLAGS_BYTES, stream);   // zero flags/progress; capture-safe
  hipLaunchKernelGGL(gru_pipe, dim3(128), dim3(512), 0, stream,
                     d_in[0], d_in[1], d_in[2], d_in[3], d_in[4],
                     (float*)d_out, (uint8_t*)d_ws);
}

// Round 4
// 34597.922 us; speedup vs baseline: 1.0100x; 1.0100x over previous
//
#include <hip/hip_runtime.h>
#include <hip/hip_bf16.h>

typedef _Float16 half_t;
typedef _Float16 half2_t __attribute__((ext_vector_type(2)));
typedef unsigned int       u32;
typedef unsigned short     u16;

#define BB    32      // batch
#define TT    2048    // seq len
#define HH    256     // hidden = input dim
#define G3    768     // 3*H
#define DEPTH 4       // ring-buffer depth (power of 2)

// ws layout (bytes) — total 856064:
//   0      : flags[3][BB][DEPTH] u32  (1536)   link: 0=S0->S1 (xg0), 1=S1->S2 (h0), 2=S2->S3 (xg1)
//   2048   : cons [3][BB]        u32  (384)    consumer progress per link
//   4096   : xg0q [BB][DEPTH][G3] f32 (393216)
//   397312 : xg1q [BB][DEPTH][G3] f32 (393216)
//   790528 : h0q  [BB][DEPTH][HH] f16 (65536)
#define OFF_CONS 2048
#define OFF_XG0  4096
#define OFF_XG1  397312
#define OFF_H0   790528
#define FLAGS_BYTES 4096

__device__ __forceinline__ half2_t f2h2(float a, float b) {
  half2_t r; r.x = (half_t)a; r.y = (half_t)b; return r;
}
__device__ __forceinline__ float sigm(float v) {
  return __builtin_amdgcn_rcpf(1.f + __builtin_amdgcn_exp2f(v * -1.4426950408889634f));
}
__device__ __forceinline__ float tanh_fast(float v) {
  return 1.f - 2.f * __builtin_amdgcn_rcpf(1.f + __builtin_amdgcn_exp2f(v * 2.8853900817779268f));
}
__device__ __forceinline__ void wait_ge(u32* p, u32 v) {
  while (__hip_atomic_load(p, __ATOMIC_ACQUIRE, __HIP_MEMORY_SCOPE_AGENT) < v)
    __builtin_amdgcn_s_sleep(1);
}

// 128 blocks: blockIdx = stage*32 + chain.
//   stage 0: xg0 = Wih0@x_t + bih0       stage 1: GRU cell layer 0 (Whh0)
//   stage 2: xg1 = Wih1@h0_t + bih1      stage 3: GRU cell layer 1 (Whh1) -> out (fp32)
// Thread (i=tid>>1, c=tid&1) owns rows {i, 256+i, 512+i} x K-half c; weights resident in
// 192 VGPRs as f16 pairs (single unconditional init path so SROA promotes the array);
// GEMV via v_dot2_f32_f16; fp32 accumulation and gate math.
__global__ __launch_bounds__(512, 2)
void gru_pipe(const float* __restrict__ x,     // fp32 [B][T][H]
              const float* __restrict__ Wih,   // fp32 [2][768][256]
              const float* __restrict__ Whh,   // fp32 [2][768][256]
              const float* __restrict__ bih,   // fp32 [2][768]
              const float* __restrict__ bhh,   // fp32 [2][768]
              float* __restrict__ out,         // fp32 [B][T][H]
              uint8_t* __restrict__ ws)
{
  const int stage = blockIdx.x >> 5;
  const int chain = blockIdx.x & 31;
  const int tid   = threadIdx.x;
  const int i     = tid >> 1;   // 0..255
  const int c     = tid & 1;    // k-half
  const int l     = stage >> 1; // layer
  const bool rec  = (stage & 1);

  u32*    flags = (u32*)ws;
  u32*    cons  = (u32*)(ws + OFF_CONS);
  float*  xg0q  = (float*)(ws + OFF_XG0);
  float*  xg1q  = (float*)(ws + OFF_XG1);
  half_t* h0q   = (half_t*)(ws + OFF_H0);

  const float* Wm = (rec ? Whh : Wih) + (size_t)l * G3 * HH;
  const float* bv = (rec ? bhh : bih) + (size_t)l * G3;

  // ---- weights -> registers (fp32 -> f16 RNE), single unconditional path ----
  half2_t w[3][64];
  float   bs[3];
#pragma unroll
  for (int r = 0; r < 3; ++r) {
    const int row = r * 256 + i;
    const float4* wp = (const float4*)(Wm + (size_t)row * HH + c * 128);
#pragma unroll
    for (int j = 0; j < 32; ++j) {
      float4 v = wp[j];
      w[r][2 * j]     = f2h2(v.x, v.y);
      w[r][2 * j + 1] = f2h2(v.z, v.w);
    }
    bs[r] = bv[row];
  }

  __shared__ __align__(16) half2_t hb[2][128];   // ping-pong input vector (256 f16)
  if (tid < 128) {
    half2_t z; z.x = (half_t)0.f; z.y = (half_t)0.f;
    hb[0][tid] = z; hb[1][tid] = z;
  }
  __syncthreads();

  float   hprev = 0.f;
  half2_t xreg; xreg.x = (half_t)0.f; xreg.y = (half_t)0.f;
  if (stage == 0 && tid < 128) {
    float2 v = ((const float2*)x)[(size_t)(chain * TT) * 128 + tid];
    xreg = f2h2(v.x, v.y);
  }

  float* xgq_in  = (stage == 1) ? xg0q : xg1q;
  float* xgq_out = (stage == 0) ? xg0q : xg1q;

  for (int t = 0; t < TT; ++t) {
    const int slot = t & (DEPTH - 1);
    float xr = 0.f, xz = 0.f, xn = 0.f;

    // ---- input / flow control ----
    if (stage == 0) {
      if (t >= DEPTH) wait_ge(&cons[chain], (u32)(t - DEPTH + 1));
      if (tid < 128) hb[t & 1][tid] = xreg;
    } else {
      wait_ge(&flags[((stage - 1) * BB + chain) * DEPTH + slot], (u32)(t + 1));
      if (stage == 2) {
        if (t >= DEPTH) wait_ge(&cons[2 * BB + chain], (u32)(t - DEPTH + 1));
        if (tid < 128) {
          u32 v = ((const u32*)(h0q + ((size_t)chain * DEPTH + slot) * HH))[tid];
          hb[t & 1][tid] = __builtin_bit_cast(half2_t, v);
        }
      } else {
        if (stage == 1 && t >= DEPTH) wait_ge(&cons[BB + chain], (u32)(t - DEPTH + 1));
        if (c == 0) {   // prefetch gate inputs; consumed after the dot loop
          const float* q = xgq_in + ((size_t)chain * DEPTH + slot) * G3;
          xr = q[i]; xz = q[256 + i]; xn = q[512 + i];
        }
      }
    }
    __syncthreads();

    // S0: prefetch next x row (overlaps the dot loop)
    if (stage == 0 && tid < 128 && t + 1 < TT) {
      float2 v = ((const float2*)x)[(size_t)(chain * TT + t + 1) * 128 + tid];
      xreg = f2h2(v.x, v.y);
    }

    // ---- GEMV: 3 rows x 128 k per thread, v_dot2_f32_f16 ----
    float a0 = 0.f, a1 = 0.f, a2 = 0.f;
    const float4* hv4 = (const float4*)&hb[t & 1][c * 64];
#pragma unroll
    for (int j4 = 0; j4 < 16; ++j4) {
      float4 q = hv4[j4];
      half2_t hh[4];
      hh[0] = __builtin_bit_cast(half2_t, q.x);
      hh[1] = __builtin_bit_cast(half2_t, q.y);
      hh[2] = __builtin_bit_cast(half2_t, q.z);
      hh[3] = __builtin_bit_cast(half2_t, q.w);
#pragma unroll
      for (int u = 0; u < 4; ++u) {
        a0 = __builtin_amdgcn_fdot2(w[0][j4 * 4 + u], hh[u], a0, false);
        a1 = __builtin_amdgcn_fdot2(w[1][j4 * 4 + u], hh[u], a1, false);
        a2 = __builtin_amdgcn_fdot2(w[2][j4 * 4 + u], hh[u], a2, false);
      }
    }
    a0 += __shfl_xor(a0, 1, 64);
    a1 += __shfl_xor(a1, 1, 64);
    a2 += __shfl_xor(a2, 1, 64);

    // ---- epilogue ----
    if (c == 0) {
      if (!rec) {
        float* q = xgq_out + ((size_t)chain * DEPTH + slot) * G3;
        q[i]       = a0 + bs[0];
        q[256 + i] = a1 + bs[1];
        q[512 + i] = a2 + bs[2];
      } else {
        float r    = sigm(xr + a0 + bs[0]);
        float z    = sigm(xz + a1 + bs[1]);
        float n    = tanh_fast(xn + r * (a2 + bs[2]));
        float hnew = n + z * (hprev - n);
        hprev = hnew;
        ((half_t*)&hb[(t + 1) & 1][0])[i] = (half_t)hnew;   // state for next step's dot
        if (stage == 1)
          h0q[((size_t)chain * DEPTH + slot) * HH + i] = (half_t)hnew;
        else
          out[(size_t)(chain * TT + t) * HH + i] = hnew;    // fp32 output
      }
    }
    __syncthreads();   // all waves' stores drained (vmcnt(0) before s_barrier) before publish

    if (tid == 0) {
      if (stage < 3)
        __hip_atomic_store(&flags[(stage * BB + chain) * DEPTH + slot], (u32)(t + 1),
                           __ATOMIC_RELEASE, __HIP_MEMORY_SCOPE_AGENT);
      if (stage > 0)
        __hip_atomic_store(&cons[(stage - 1) * BB + chain], (u32)(t + 1),
                           __ATOMIC_RELAXED, __HIP_MEMORY_SCOPE_AGENT);
    }
  }
}

extern "C" void kernel_launch(void* const* d_in, const int* in_sizes, int n_in,
                              void* d_out, int out_size, void* d_ws, size_t ws_size,
                              hipStream_t stream) {
  hipMemsetAsync(d_ws, 0, FLAGS_BYTES, stream);   // zero flags/progress; capture-safe
  hipLaunchKernelGGL(gru_pipe, dim3(128), dim3(512), 0, stream,
                     (const float*)d_in[0], (const float*)d_in[1], (const float*)d_in[2],
                     (const float*)d_in[3], (const float*)d_in[4],
                     (float*)d_out, (uint8_t*)d_ws);
}

// Round 5
// 34440.143 us; speedup vs baseline: 1.0147x; 1.0046x over previous
//
#include <hip/hip_runtime.h>
#include <hip/hip_bf16.h>

typedef _Float16 half_t;
typedef _Float16 half2_t __attribute__((ext_vector_type(2)));
typedef unsigned int       u32;
typedef unsigned short     u16;

#define BB    32      // batch
#define TT    2048    // seq len
#define HH    256     // hidden = input dim
#define G3    768     // 3*H
#define DEPTH 4       // ring-buffer depth (power of 2)

// ws layout (bytes) — total 856064:
//   0      : flags[3][BB][DEPTH] u32  (1536)   link: 0=S0->S1 (xg0), 1=S1->S2 (h0), 2=S2->S3 (xg1)
//   2048   : cons [3][BB]        u32  (384)    consumer progress per link
//   4096   : xg0q [BB][DEPTH][G3] f32 (393216)
//   397312 : xg1q [BB][DEPTH][G3] f32 (393216)
//   790528 : h0q  [BB][DEPTH][HH] f16 (65536)
#define OFF_CONS 2048
#define OFF_XG0  4096
#define OFF_XG1  397312
#define OFF_H0   790528
#define FLAGS_BYTES 4096

__device__ __forceinline__ half2_t f2h2(float a, float b) {
  half2_t r; r.x = (half_t)a; r.y = (half_t)b; return r;
}
__device__ __forceinline__ float sigm(float v) {
  return __builtin_amdgcn_rcpf(1.f + __builtin_amdgcn_exp2f(v * -1.4426950408889634f));
}
__device__ __forceinline__ float tanh_fast(float v) {
  return 1.f - 2.f * __builtin_amdgcn_rcpf(1.f + __builtin_amdgcn_exp2f(v * 2.8853900817779268f));
}
__device__ __forceinline__ void wait_ge(u32* p, u32 v) {
  while (__hip_atomic_load(p, __ATOMIC_ACQUIRE, __HIP_MEMORY_SCOPE_AGENT) < v)
    __builtin_amdgcn_s_sleep(1);
}

// 128 blocks: blockIdx = stage*32 + chain.
//   stage 0: xg0 = Wih0@x_t + bih0       stage 1: GRU cell layer 0 (Whh0)
//   stage 2: xg1 = Wih1@h0_t + bih1      stage 3: GRU cell layer 1 (Whh1) -> out (fp32)
// Thread (i=tid>>1, c=tid&1) owns rows {i, 256+i, 512+i} x K-half c; weights resident in
// 192 VGPRs as f16 pairs. amdgpu_waves_per_eu(2,2) pins occupancy at 2 waves/EU so the
// RA gets a 256-VGPR budget — without the max, the backend targeted 4 waves/EU (128 VGPR)
// and spilled the weight array to scratch (R3/R4: VGPR_Count=128, 16.9us/step).
__global__ __launch_bounds__(512) __attribute__((amdgpu_waves_per_eu(2, 2)))
void gru_pipe(const float* __restrict__ x,     // fp32 [B][T][H]
              const float* __restrict__ Wih,   // fp32 [2][768][256]
              const float* __restrict__ Whh,   // fp32 [2][768][256]
              const float* __restrict__ bih,   // fp32 [2][768]
              const float* __restrict__ bhh,   // fp32 [2][768]
              float* __restrict__ out,         // fp32 [B][T][H]
              uint8_t* __restrict__ ws)
{
  const int stage = blockIdx.x >> 5;
  const int chain = blockIdx.x & 31;
  const int tid   = threadIdx.x;
  const int i     = tid >> 1;   // 0..255
  const int c     = tid & 1;    // k-half
  const int l     = stage >> 1; // layer
  const bool rec  = (stage & 1);

  u32*    flags = (u32*)ws;
  u32*    cons  = (u32*)(ws + OFF_CONS);
  float*  xg0q  = (float*)(ws + OFF_XG0);
  float*  xg1q  = (float*)(ws + OFF_XG1);
  half_t* h0q   = (half_t*)(ws + OFF_H0);

  const float* Wm = (rec ? Whh : Wih) + (size_t)l * G3 * HH;
  const float* bv = (rec ? bhh : bih) + (size_t)l * G3;

  // ---- weights -> registers (fp32 -> f16 RNE), single unconditional path ----
  half2_t w[3][64];
  float   bs[3];
#pragma unroll
  for (int r = 0; r < 3; ++r) {
    const int row = r * 256 + i;
    const float4* wp = (const float4*)(Wm + (size_t)row * HH + c * 128);
#pragma unroll
    for (int j = 0; j < 32; ++j) {
      float4 v = wp[j];
      w[r][2 * j]     = f2h2(v.x, v.y);
      w[r][2 * j + 1] = f2h2(v.z, v.w);
    }
    bs[r] = bv[row];
  }

  __shared__ __align__(16) half2_t hb[2][128];   // ping-pong input vector (256 f16)
  if (tid < 128) {
    half2_t z; z.x = (half_t)0.f; z.y = (half_t)0.f;
    hb[0][tid] = z; hb[1][tid] = z;
  }
  __syncthreads();

  float   hprev = 0.f;
  half2_t xreg; xreg.x = (half_t)0.f; xreg.y = (half_t)0.f;
  if (stage == 0 && tid < 128) {
    float2 v = ((const float2*)x)[(size_t)(chain * TT) * 128 + tid];
    xreg = f2h2(v.x, v.y);
  }

  float* xgq_in  = (stage == 1) ? xg0q : xg1q;
  float* xgq_out = (stage == 0) ? xg0q : xg1q;

  for (int t = 0; t < TT; ++t) {
    const int slot = t & (DEPTH - 1);
    float xr = 0.f, xz = 0.f, xn = 0.f;

    // ---- input / flow control ----
    if (stage == 0) {
      if (t >= DEPTH) wait_ge(&cons[chain], (u32)(t - DEPTH + 1));
      if (tid < 128) hb[t & 1][tid] = xreg;
    } else {
      wait_ge(&flags[((stage - 1) * BB + chain) * DEPTH + slot], (u32)(t + 1));
      if (stage == 2) {
        if (t >= DEPTH) wait_ge(&cons[2 * BB + chain], (u32)(t - DEPTH + 1));
        if (tid < 128) {
          u32 v = ((const u32*)(h0q + ((size_t)chain * DEPTH + slot) * HH))[tid];
          hb[t & 1][tid] = __builtin_bit_cast(half2_t, v);
        }
      } else {
        if (stage == 1 && t >= DEPTH) wait_ge(&cons[BB + chain], (u32)(t - DEPTH + 1));
        if (c == 0) {   // prefetch gate inputs; consumed after the dot loop
          const float* q = xgq_in + ((size_t)chain * DEPTH + slot) * G3;
          xr = q[i]; xz = q[256 + i]; xn = q[512 + i];
        }
      }
    }
    __syncthreads();

    // S0: prefetch next x row (overlaps the dot loop)
    if (stage == 0 && tid < 128 && t + 1 < TT) {
      float2 v = ((const float2*)x)[(size_t)(chain * TT + t + 1) * 128 + tid];
      xreg = f2h2(v.x, v.y);
    }

    // ---- GEMV: 3 rows x 128 k per thread, v_dot2_f32_f16 ----
    float a0 = 0.f, a1 = 0.f, a2 = 0.f;
    const float4* hv4 = (const float4*)&hb[t & 1][c * 64];
#pragma unroll
    for (int j4 = 0; j4 < 16; ++j4) {
      float4 q = hv4[j4];
      half2_t hh[4];
      hh[0] = __builtin_bit_cast(half2_t, q.x);
      hh[1] = __builtin_bit_cast(half2_t, q.y);
      hh[2] = __builtin_bit_cast(half2_t, q.z);
      hh[3] = __builtin_bit_cast(half2_t, q.w);
#pragma unroll
      for (int u = 0; u < 4; ++u) {
        a0 = __builtin_amdgcn_fdot2(w[0][j4 * 4 + u], hh[u], a0, false);
        a1 = __builtin_amdgcn_fdot2(w[1][j4 * 4 + u], hh[u], a1, false);
        a2 = __builtin_amdgcn_fdot2(w[2][j4 * 4 + u], hh[u], a2, false);
      }
    }
    a0 += __shfl_xor(a0, 1, 64);
    a1 += __shfl_xor(a1, 1, 64);
    a2 += __shfl_xor(a2, 1, 64);

    // ---- epilogue ----
    if (c == 0) {
      if (!rec) {
        float* q = xgq_out + ((size_t)chain * DEPTH + slot) * G3;
        q[i]       = a0 + bs[0];
        q[256 + i] = a1 + bs[1];
        q[512 + i] = a2 + bs[2];
      } else {
        float r    = sigm(xr + a0 + bs[0]);
        float z    = sigm(xz + a1 + bs[1]);
        float n    = tanh_fast(xn + r * (a2 + bs[2]));
        float hnew = n + z * (hprev - n);
        hprev = hnew;
        ((half_t*)&hb[(t + 1) & 1][0])[i] = (half_t)hnew;   // state for next step's dot
        if (stage == 1)
          h0q[((size_t)chain * DEPTH + slot) * HH + i] = (half_t)hnew;
        else
          out[(size_t)(chain * TT + t) * HH + i] = hnew;    // fp32 output
      }
    }
    __syncthreads();   // all waves' stores drained (vmcnt(0) before s_barrier) before publish

    if (tid == 0) {
      if (stage < 3)
        __hip_atomic_store(&flags[(stage * BB + chain) * DEPTH + slot], (u32)(t + 1),
                           __ATOMIC_RELEASE, __HIP_MEMORY_SCOPE_AGENT);
      if (stage > 0)
        __hip_atomic_store(&cons[(stage - 1) * BB + chain], (u32)(t + 1),
                           __ATOMIC_RELAXED, __HIP_MEMORY_SCOPE_AGENT);
    }
  }
}

extern "C" void kernel_launch(void* const* d_in, const int* in_sizes, int n_in,
                              void* d_out, int out_size, void* d_ws, size_t ws_size,
                              hipStream_t stream) {
  hipMemsetAsync(d_ws, 0, FLAGS_BYTES, stream);   // zero flags/progress; capture-safe
  hipLaunchKernelGGL(gru_pipe, dim3(128), dim3(512), 0, stream,
                     (const float*)d_in[0], (const float*)d_in[1], (const float*)d_in[2],
                     (const float*)d_in[3], (const float*)d_in[4],
                     (float*)d_out, (uint8_t*)d_ws);
}

// Round 6
// 9945.219 us; speedup vs baseline: 3.5138x; 3.4630x over previous
//
#include <hip/hip_runtime.h>

typedef _Float16 half_t;
typedef _Float16 half2_t __attribute__((ext_vector_type(2)));
typedef unsigned int       u32;
typedef unsigned short     u16;
typedef u32 wvec16 __attribute__((ext_vector_type(16)));

#define BB    32      // batch
#define TT    2048    // seq len
#define HH    256     // hidden = input dim
#define G3    768     // 3*H
#define DEPTH 8       // ring-buffer depth (power of 2)

// ws layout (bytes), ~1.65 MB total:
//   0       : flags[3][BB] padded 128B each (slot = u32[DEPTH] in first 32B)   (12288)
//   12288   : cons [3][BB] padded 128B each                                    (12288)
//   24576   : xg0q [BB][DEPTH][G3] f32   (786432)
//   811008  : xg1q [BB][DEPTH][G3] f32   (786432)
//   1597440 : h0q  [BB][DEPTH][HH] f16   (131072)
#define OFF_CONS 12288
#define OFF_XG0  24576
#define OFF_XG1  811008
#define OFF_H0   1597440
#define FLAGS_BYTES 24576

__device__ __forceinline__ half2_t f2h2(float a, float b) {
  half2_t r; r.x = (half_t)a; r.y = (half_t)b; return r;
}
__device__ __forceinline__ float sigm(float v) {
  return __builtin_amdgcn_rcpf(1.f + __builtin_amdgcn_exp2f(v * -1.4426950408889634f));
}
__device__ __forceinline__ float tanh_fast(float v) {
  return 1.f - 2.f * __builtin_amdgcn_rcpf(1.f + __builtin_amdgcn_exp2f(v * 2.8853900817779268f));
}
__device__ __forceinline__ void wait_ge(u32* p, u32 v) {
  while (__hip_atomic_load(p, __ATOMIC_ACQUIRE, __HIP_MEMORY_SCOPE_AGENT) < v)
    __builtin_amdgcn_s_sleep(1);
}
__device__ __forceinline__ float ld_f32_agent(const float* p) {
  return __hip_atomic_load(p, __ATOMIC_RELAXED, __HIP_MEMORY_SCOPE_AGENT);
}
__device__ __forceinline__ u32 ld_u32_agent(const u32* p) {
  return __hip_atomic_load(p, __ATOMIC_RELAXED, __HIP_MEMORY_SCOPE_AGENT);
}
__device__ __forceinline__ void st_f32_agent(float* p, float v) {
  __hip_atomic_store(p, v, __ATOMIC_RELAXED, __HIP_MEMORY_SCOPE_AGENT);
}
__device__ __forceinline__ void st_u16_agent(u16* p, u16 v) {
  __hip_atomic_store(p, v, __ATOMIC_RELAXED, __HIP_MEMORY_SCOPE_AGENT);
}

// 128 blocks: blockIdx = stage*32 + chain (all 4 stages of a chain ≡ chain mod 8 → same XCD).
//   stage 0: xg0 = Wih0@x_t + bih0       stage 1: GRU cell layer 0 (Whh0)
//   stage 2: xg1 = Wih1@h0_t + bih1      stage 3: GRU cell layer 1 (Whh1) -> out (fp32)
// 1024 threads: thread (i=tid>>2, c=tid&3) owns rows {i,256+i,512+i} x k in [c*64,(c+1)*64).
// Weights = 96 VGPRs/thread as 6 x u32x16 ext-vectors (SSA — no scratch path), fitting the
// backend's 128-VGPR @ 4 waves/EU allocation that R3-R5 showed it insists on.
// Protocol: tid0-only flag polling; payload via relaxed agent-scope atomics (L1-bypass).
__global__ __launch_bounds__(1024, 4)
void gru_pipe(const float* __restrict__ x,     // fp32 [B][T][H]
              const float* __restrict__ Wih,   // fp32 [2][768][256]
              const float* __restrict__ Whh,   // fp32 [2][768][256]
              const float* __restrict__ bih,   // fp32 [2][768]
              const float* __restrict__ bhh,   // fp32 [2][768]
              float* __restrict__ out,         // fp32 [B][T][H]
              uint8_t* __restrict__ ws)
{
  const int stage = blockIdx.x >> 5;
  const int chain = blockIdx.x & 31;
  const int tid   = threadIdx.x;
  const int i     = tid >> 2;   // 0..255
  const int c     = tid & 3;    // k-quarter
  const int l     = stage >> 1; // layer
  const bool rec  = (stage & 1);

  u32*    flags = (u32*)ws;                  // [(link*32+chain)*32 + slot]
  u32*    cons  = (u32*)(ws + OFF_CONS);     // [(link*32+chain)*32]
  float*  xg0q  = (float*)(ws + OFF_XG0);
  float*  xg1q  = (float*)(ws + OFF_XG1);
  half_t* h0q   = (half_t*)(ws + OFF_H0);

  const float* Wm = (rec ? Whh : Wih) + (size_t)l * G3 * HH;
  const float* bv = (rec ? bhh : bih) + (size_t)l * G3;

  // ---- weights -> 6 x u32x16 vectors (96 VGPRs), fp32 -> f16 RNE ----
  wvec16 wv[6];
  float  bs[3];
#pragma unroll
  for (int r = 0; r < 3; ++r) {
    const int row = r * 256 + i;
    const float4* wp = (const float4*)(Wm + (size_t)row * HH + c * 64);
#pragma unroll
    for (int v2 = 0; v2 < 2; ++v2) {
      wvec16 acc;
#pragma unroll
      for (int j = 0; j < 8; ++j) {
        float4 q = wp[v2 * 8 + j];
        acc[j * 2]     = __builtin_bit_cast(u32, f2h2(q.x, q.y));
        acc[j * 2 + 1] = __builtin_bit_cast(u32, f2h2(q.z, q.w));
      }
      wv[r * 2 + v2] = acc;
    }
    bs[r] = bv[row];
  }

  __shared__ __align__(16) half2_t hb[2][128];   // ping-pong input vector (256 f16)
  if (tid < 128) {
    half2_t z; z.x = (half_t)0.f; z.y = (half_t)0.f;
    hb[0][tid] = z; hb[1][tid] = z;
  }

  float   hprev = 0.f;
  half2_t xreg; xreg.x = (half_t)0.f; xreg.y = (half_t)0.f;
  if (stage == 0 && tid < 128) {
    float2 v = ((const float2*)(x + (size_t)(chain * TT) * HH))[tid];
    xreg = f2h2(v.x, v.y);
  }

  float* xgq_in  = (stage == 1) ? xg0q : xg1q;
  float* xgq_out = (stage == 0) ? xg0q : xg1q;
  u32* flag_in   = flags + ((size_t)((stage - 1) * BB + chain)) * 32;  // valid for stage>0
  u32* flag_out  = flags + ((size_t)(stage * BB + chain)) * 32;        // valid for stage<3
  u32* cons_in   = cons + ((size_t)((stage - 1) * BB + chain)) * 32;
  u32* cons_out  = cons + ((size_t)(stage * BB + chain)) * 32;

  __syncthreads();

  for (int t = 0; t < TT; ++t) {
    const int slot = t & (DEPTH - 1);
    float xr = 0.f, xz = 0.f, xn = 0.f;

    // ---- protocol waits: single poller ----
    if (tid == 0) {
      if (stage > 0) wait_ge(flag_in + slot, (u32)(t + 1));
      if (stage < 3 && t >= DEPTH) wait_ge(cons_out, (u32)(t - DEPTH + 1));
    }
    __syncthreads();   // B1: block released once data ready

    // ---- payload reads (agent scope = L1 bypass) / LDS fill ----
    if (stage == 0) {
      if (tid < 128) hb[t & 1][tid] = xreg;
    } else if (stage == 2) {
      if (tid < 128) {
        u32 v = ld_u32_agent((const u32*)(h0q + ((size_t)chain * DEPTH + slot) * HH) + tid);
        hb[t & 1][tid] = __builtin_bit_cast(half2_t, v);
      }
    } else {
      if (c == 0) {   // gate inputs; consumed in epilogue (latency hidden by dot)
        const float* q = xgq_in + ((size_t)chain * DEPTH + slot) * G3;
        xr = ld_f32_agent(q + i);
        xz = ld_f32_agent(q + 256 + i);
        xn = ld_f32_agent(q + 512 + i);
      }
    }
    __syncthreads();   // B2: hb fill visible

    // S0: prefetch next x row (plain loads; overlaps the dot)
    if (stage == 0 && tid < 128 && t + 1 < TT) {
      float2 v = ((const float2*)(x + (size_t)(chain * TT + t + 1) * HH))[tid];
      xreg = f2h2(v.x, v.y);
    }

    // ---- GEMV: 3 rows x 64 k per thread, v_dot2_f32_f16 ----
    float a0 = 0.f, a1 = 0.f, a2 = 0.f;
    const float4* hv4 = (const float4*)&hb[t & 1][c * 32];
#pragma unroll
    for (int j4 = 0; j4 < 8; ++j4) {
      float4 q = hv4[j4];
      half2_t hh[4];
      hh[0] = __builtin_bit_cast(half2_t, q.x);
      hh[1] = __builtin_bit_cast(half2_t, q.y);
      hh[2] = __builtin_bit_cast(half2_t, q.z);
      hh[3] = __builtin_bit_cast(half2_t, q.w);
#pragma unroll
      for (int u = 0; u < 4; ++u) {
        const int idx = j4 * 4 + u;          // 0..31 (half2 index within row slice)
        const int hi  = idx >> 4, ei = idx & 15;
        a0 = __builtin_amdgcn_fdot2(__builtin_bit_cast(half2_t, (u32)wv[0 + hi][ei]), hh[u], a0, false);
        a1 = __builtin_amdgcn_fdot2(__builtin_bit_cast(half2_t, (u32)wv[2 + hi][ei]), hh[u], a1, false);
        a2 = __builtin_amdgcn_fdot2(__builtin_bit_cast(half2_t, (u32)wv[4 + hi][ei]), hh[u], a2, false);
      }
    }
    // butterfly over the 4 k-quarters (lanes c, c^1, c^2)
    a0 += __shfl_xor(a0, 1, 64); a0 += __shfl_xor(a0, 2, 64);
    a1 += __shfl_xor(a1, 1, 64); a1 += __shfl_xor(a1, 2, 64);
    a2 += __shfl_xor(a2, 1, 64); a2 += __shfl_xor(a2, 2, 64);

    // ---- epilogue ----
    if (c == 0) {
      if (!rec) {
        float* q = xgq_out + ((size_t)chain * DEPTH + slot) * G3;
        st_f32_agent(q + i,       a0 + bs[0]);
        st_f32_agent(q + 256 + i, a1 + bs[1]);
        st_f32_agent(q + 512 + i, a2 + bs[2]);
      } else {
        float r    = sigm(xr + a0 + bs[0]);
        float z    = sigm(xz + a1 + bs[1]);
        float n    = tanh_fast(xn + r * (a2 + bs[2]));
        float hnew = n + z * (hprev - n);
        hprev = hnew;
        ((half_t*)&hb[(t + 1) & 1][0])[i] = (half_t)hnew;   // state for next step's dot
        if (stage == 1) {
          half_t hv = (half_t)hnew;
          st_u16_agent((u16*)(h0q + ((size_t)chain * DEPTH + slot) * HH + i),
                       __builtin_bit_cast(u16, hv));
        } else {
          out[(size_t)(chain * TT + t) * HH + i] = hnew;    // fp32 output
        }
      }
    }
    __syncthreads();   // B3: all waves' stores drained (vmcnt(0) before s_barrier)

    if (tid == 0) {
      if (stage < 3)
        __hip_atomic_store(flag_out + slot, (u32)(t + 1),
                           __ATOMIC_RELEASE, __HIP_MEMORY_SCOPE_AGENT);
      if (stage > 0)
        __hip_atomic_store(cons_in, (u32)(t + 1),
                           __ATOMIC_RELAXED, __HIP_MEMORY_SCOPE_AGENT);
    }
  }
}

extern "C" void kernel_launch(void* const* d_in, const int* in_sizes, int n_in,
                              void* d_out, int out_size, void* d_ws, size_t ws_size,
                              hipStream_t stream) {
  hipMemsetAsync(d_ws, 0, FLAGS_BYTES, stream);   // zero flags/credits; capture-safe
  hipLaunchKernelGGL(gru_pipe, dim3(128), dim3(1024), 0, stream,
                     (const float*)d_in[0], (const float*)d_in[1], (const float*)d_in[2],
                     (const float*)d_in[3], (const float*)d_in[4],
                     (float*)d_out, (uint8_t*)d_ws);
}

// Round 7
// 7939.006 us; speedup vs baseline: 4.4017x; 1.2527x over previous
//
#include <hip/hip_runtime.h>

typedef _Float16 half_t;
typedef _Float16 half2_t __attribute__((ext_vector_type(2)));
typedef unsigned int       u32;
typedef unsigned short     u16;

#define BB    32      // batch
#define TT    2048    // seq len
#define HH    256     // hidden = input dim
#define G3    768     // 3*H
#define DEPTH 8       // ring-buffer depth (power of 2)

// ws layout (bytes), ~1.65 MB total:
//   0       : flags[3][BB] padded 128B each (slot = u32[DEPTH] in first 32B)   (12288)
//   12288   : cons [3][BB] padded 128B each                                    (12288)
//   24576   : xg0q [BB][DEPTH][G3] f32   (786432)
//   811008  : xg1q [BB][DEPTH][G3] f32   (786432)
//   1597440 : h0q  [BB][DEPTH][HH] f16   (131072)
#define OFF_CONS 12288
#define OFF_XG0  24576
#define OFF_XG1  811008
#define OFF_H0   1597440
#define FLAGS_BYTES 24576

__device__ __forceinline__ half2_t f2h2(float a, float b) {
  half2_t r; r.x = (half_t)a; r.y = (half_t)b; return r;
}
__device__ __forceinline__ float sigm(float v) {
  return __builtin_amdgcn_rcpf(1.f + __builtin_amdgcn_exp2f(v * -1.4426950408889634f));
}
__device__ __forceinline__ float tanh_fast(float v) {
  return 1.f - 2.f * __builtin_amdgcn_rcpf(1.f + __builtin_amdgcn_exp2f(v * 2.8853900817779268f));
}
__device__ __forceinline__ void wait_ge(u32* p, u32 v) {
  while (__hip_atomic_load(p, __ATOMIC_ACQUIRE, __HIP_MEMORY_SCOPE_AGENT) < v)
    __builtin_amdgcn_s_sleep(1);
}
__device__ __forceinline__ float ld_f32_agent(const float* p) {
  return __hip_atomic_load(p, __ATOMIC_RELAXED, __HIP_MEMORY_SCOPE_AGENT);
}
__device__ __forceinline__ u32 ld_u32_agent(const u32* p) {
  return __hip_atomic_load(p, __ATOMIC_RELAXED, __HIP_MEMORY_SCOPE_AGENT);
}
__device__ __forceinline__ void st_f32_agent(float* p, float v) {
  __hip_atomic_store(p, v, __ATOMIC_RELAXED, __HIP_MEMORY_SCOPE_AGENT);
}
__device__ __forceinline__ void st_u16_agent(u16* p, u16 v) {
  __hip_atomic_store(p, v, __ATOMIC_RELAXED, __HIP_MEMORY_SCOPE_AGENT);
}

// 128 blocks: blockIdx = stage*32 + chain.
//   stage 0: xg0 = Wih0@x_t + bih0       stage 1: GRU cell layer 0 (Whh0)
//   stage 2: xg1 = Wih1@h0_t + bih1      stage 3: GRU cell layer 1 (Whh1) -> out (fp32)
// 512 threads: thread (i=tid>>1, c=tid&1) owns rows {i,256+i,512+i} x K-half c.
// Weights = 192 VGPRs/thread as f16 pairs. R6 showed the compiler REMATERIALIZES the
// weight loads inside the t-loop (VGPR_Count=64, 384KB/step L2 restream) — so after the
// init loads, every weight register is laundered through an empty asm() to erase its
// memory provenance: the RA must keep them live. waves_per_eu(2,2) grants a 256-VGPR
// budget (512 thr = 8 waves = 2/SIMD at 1 block/CU).
__global__ __launch_bounds__(512) __attribute__((amdgpu_waves_per_eu(2, 2)))
void gru_pipe(const float* __restrict__ x,     // fp32 [B][T][H]
              const float* __restrict__ Wih,   // fp32 [2][768][256]
              const float* __restrict__ Whh,   // fp32 [2][768][256]
              const float* __restrict__ bih,   // fp32 [2][768]
              const float* __restrict__ bhh,   // fp32 [2][768]
              float* __restrict__ out,         // fp32 [B][T][H]
              uint8_t* __restrict__ ws)
{
  const int stage = blockIdx.x >> 5;
  const int chain = blockIdx.x & 31;
  const int tid   = threadIdx.x;
  const int i     = tid >> 1;   // 0..255
  const int c     = tid & 1;    // k-half
  const int l     = stage >> 1; // layer
  const bool rec  = (stage & 1);

  u32*    flags = (u32*)ws;                  // [(link*32+chain)*32 + slot]
  u32*    cons  = (u32*)(ws + OFF_CONS);     // [(link*32+chain)*32]
  float*  xg0q  = (float*)(ws + OFF_XG0);
  float*  xg1q  = (float*)(ws + OFF_XG1);
  half_t* h0q   = (half_t*)(ws + OFF_H0);

  const float* Wm = (rec ? Whh : Wih) + (size_t)l * G3 * HH;
  const float* bv = (rec ? bhh : bih) + (size_t)l * G3;

  // ---- weights -> 192 VGPRs (fp32 -> f16 RNE), then launder via asm so the
  //      compiler cannot rematerialize the loads inside the t-loop ----
  u32   w[3][64];
  float bs[3];
#pragma unroll
  for (int r = 0; r < 3; ++r) {
    const int row = r * 256 + i;
    const float4* wp = (const float4*)(Wm + (size_t)row * HH + c * 128);
#pragma unroll
    for (int j = 0; j < 32; ++j) {
      float4 v = wp[j];
      w[r][2 * j]     = __builtin_bit_cast(u32, f2h2(v.x, v.y));
      w[r][2 * j + 1] = __builtin_bit_cast(u32, f2h2(v.z, v.w));
    }
    bs[r] = bv[row];
  }
#pragma unroll
  for (int r = 0; r < 3; ++r)
#pragma unroll
    for (int j = 0; j < 64; ++j)
      asm volatile("" : "+v"(w[r][j]));   // opaque: no memory provenance, must stay live

  __shared__ __align__(16) half2_t hb[2][128];   // ping-pong input vector (256 f16)
  if (tid < 128) {
    half2_t z; z.x = (half_t)0.f; z.y = (half_t)0.f;
    hb[0][tid] = z; hb[1][tid] = z;
  }

  float   hprev = 0.f;
  half2_t xreg; xreg.x = (half_t)0.f; xreg.y = (half_t)0.f;
  if (stage == 0 && tid < 128) {
    float2 v = ((const float2*)(x + (size_t)(chain * TT) * HH))[tid];
    xreg = f2h2(v.x, v.y);
  }

  float* xgq_in  = (stage == 1) ? xg0q : xg1q;
  float* xgq_out = (stage == 0) ? xg0q : xg1q;
  u32* flag_in   = flags + ((size_t)((stage - 1) * BB + chain)) * 32;  // stage>0
  u32* flag_out  = flags + ((size_t)(stage * BB + chain)) * 32;        // stage<3
  u32* cons_in   = cons + ((size_t)((stage - 1) * BB + chain)) * 32;
  u32* cons_out  = cons + ((size_t)(stage * BB + chain)) * 32;

  __syncthreads();

  for (int t = 0; t < TT; ++t) {
    const int slot = t & (DEPTH - 1);
    float xr = 0.f, xz = 0.f, xn = 0.f;

    // ---- protocol waits: single poller ----
    if (tid == 0) {
      if (stage > 0) wait_ge(flag_in + slot, (u32)(t + 1));
      if (stage < 3 && t >= DEPTH) wait_ge(cons_out, (u32)(t - DEPTH + 1));
    }
    __syncthreads();   // B1: block released once data ready

    // ---- payload reads (agent scope = L1 bypass) / LDS fill ----
    if (stage == 0) {
      if (tid < 128) hb[t & 1][tid] = xreg;
    } else if (stage == 2) {
      if (tid < 128) {
        u32 v = ld_u32_agent((const u32*)(h0q + ((size_t)chain * DEPTH + slot) * HH) + tid);
        hb[t & 1][tid] = __builtin_bit_cast(half2_t, v);
      }
    } else {
      if (c == 0) {   // gate inputs; consumed in epilogue (latency hidden by dot)
        const float* q = xgq_in + ((size_t)chain * DEPTH + slot) * G3;
        xr = ld_f32_agent(q + i);
        xz = ld_f32_agent(q + 256 + i);
        xn = ld_f32_agent(q + 512 + i);
      }
    }
    __syncthreads();   // B2: hb fill visible

    // S0: prefetch next x row (plain loads; overlaps the dot)
    if (stage == 0 && tid < 128 && t + 1 < TT) {
      float2 v = ((const float2*)(x + (size_t)(chain * TT + t + 1) * HH))[tid];
      xreg = f2h2(v.x, v.y);
    }

    // ---- GEMV: 3 rows x 128 k per thread, v_dot2_f32_f16 ----
    float a0 = 0.f, a1 = 0.f, a2 = 0.f;
    const float4* hv4 = (const float4*)&hb[t & 1][c * 64];
#pragma unroll
    for (int j4 = 0; j4 < 16; ++j4) {
      float4 q = hv4[j4];
      half2_t hh[4];
      hh[0] = __builtin_bit_cast(half2_t, q.x);
      hh[1] = __builtin_bit_cast(half2_t, q.y);
      hh[2] = __builtin_bit_cast(half2_t, q.z);
      hh[3] = __builtin_bit_cast(half2_t, q.w);
#pragma unroll
      for (int u = 0; u < 4; ++u) {
        const int idx = j4 * 4 + u;
        a0 = __builtin_amdgcn_fdot2(__builtin_bit_cast(half2_t, w[0][idx]), hh[u], a0, false);
        a1 = __builtin_amdgcn_fdot2(__builtin_bit_cast(half2_t, w[1][idx]), hh[u], a1, false);
        a2 = __builtin_amdgcn_fdot2(__builtin_bit_cast(half2_t, w[2][idx]), hh[u], a2, false);
      }
    }
    a0 += __shfl_xor(a0, 1, 64);
    a1 += __shfl_xor(a1, 1, 64);
    a2 += __shfl_xor(a2, 1, 64);

    // ---- epilogue ----
    if (c == 0) {
      if (!rec) {
        float* q = xgq_out + ((size_t)chain * DEPTH + slot) * G3;
        st_f32_agent(q + i,       a0 + bs[0]);
        st_f32_agent(q + 256 + i, a1 + bs[1]);
        st_f32_agent(q + 512 + i, a2 + bs[2]);
      } else {
        float r    = sigm(xr + a0 + bs[0]);
        float z    = sigm(xz + a1 + bs[1]);
        float n    = tanh_fast(xn + r * (a2 + bs[2]));
        float hnew = n + z * (hprev - n);
        hprev = hnew;
        ((half_t*)&hb[(t + 1) & 1][0])[i] = (half_t)hnew;   // state for next step's dot
        if (stage == 1) {
          half_t hv = (half_t)hnew;
          st_u16_agent((u16*)(h0q + ((size_t)chain * DEPTH + slot) * HH + i),
                       __builtin_bit_cast(u16, hv));
        } else {
          out[(size_t)(chain * TT + t) * HH + i] = hnew;    // fp32 output
        }
      }
    }
    __syncthreads();   // B3: all waves' stores drained (vmcnt(0) before s_barrier)

    if (tid == 0) {
      if (stage < 3)
        __hip_atomic_store(flag_out + slot, (u32)(t + 1),
                           __ATOMIC_RELEASE, __HIP_MEMORY_SCOPE_AGENT);
      if (stage > 0)
        __hip_atomic_store(cons_in, (u32)(t + 1),
                           __ATOMIC_RELAXED, __HIP_MEMORY_SCOPE_AGENT);
    }
  }
}

extern "C" void kernel_launch(void* const* d_in, const int* in_sizes, int n_in,
                              void* d_out, int out_size, void* d_ws, size_t ws_size,
                              hipStream_t stream) {
  hipMemsetAsync(d_ws, 0, FLAGS_BYTES, stream);   // zero flags/credits; capture-safe
  hipLaunchKernelGGL(gru_pipe, dim3(128), dim3(512), 0, stream,
                     (const float*)d_in[0], (const float*)d_in[1], (const float*)d_in[2],
                     (const float*)d_in[3], (const float*)d_in[4],
                     (float*)d_out, (uint8_t*)d_ws);
}